// Round 8
// baseline (444.742 us; speedup 1.0000x reference)
//
#include <hip/hip_runtime.h>

#define N_PTS   200000
#define N_EDGES 1600000
#define MEM_SIZE (1 << 27)

#define COPY_BLOCKS  32768                    // 33,554,432 float4 / (256 thr * 4 per thr)
#define F4_PER_BLOCK 1024

#define NP  25                                // node parts
#define NPB 8192                              // nodes per part (25*8192 >= 200000); 64KB LDS
#define EP  16                                // edge parts
#define EPS (N_EDGES / EP)                    // 100000 edges per slice

// Per-(edge-slice, node-range) 2-min in LDS; ZERO global atomics.
// Classic rtn-min 2-min: old=atomicMin(min1,i); cand=(i<old)?old:i; atomicMin(min2,cand).
// Block (np,ep) owns W[ep][np-range] exclusively -> plain coalesced stores.
__global__ __launch_bounds__(256) void scan_2min(const int2* __restrict__ edges,
                                                 unsigned long long* __restrict__ W) {
    __shared__ unsigned mn1[NPB];
    __shared__ unsigned mn2[NPB];

    int b  = blockIdx.x;
    int ep = b / NP;                 // consecutive blocks share an edge slice (L2 reuse)
    int np = b % NP;
    int lo = np * NPB;

    for (int j = threadIdx.x; j < NPB; j += 256) { mn1[j] = 0xFFFFFFFFu; mn2[j] = 0xFFFFFFFFu; }
    __syncthreads();

    int e0 = ep * EPS;
    for (int k = threadIdx.x; k < EPS; k += 256) {
        int i = e0 + k;
        int2 e = edges[i];
        unsigned ia = (unsigned)i;                 // forward half-edge (src = e.x)
        unsigned ib = (unsigned)(i + N_EDGES);     // reverse half-edge (src = e.y)
        int ax = e.x - lo;
        if ((unsigned)ax < NPB) {
            unsigned old = atomicMin(&mn1[ax], ia);
            unsigned c = (ia < old) ? old : ia;    // displaced value or losing insert
            if (c != 0xFFFFFFFFu) atomicMin(&mn2[ax], c);
        }
        int ay = e.y - lo;
        if ((unsigned)ay < NPB) {
            unsigned old = atomicMin(&mn1[ay], ib);
            unsigned c = (ib < old) ? old : ib;
            if (c != 0xFFFFFFFFu) atomicMin(&mn2[ay], c);
        }
    }
    __syncthreads();

    for (int j = threadIdx.x; j < NPB; j += 256) {
        int n = lo + j;
        if (n < N_PTS)
            W[(size_t)ep * N_PTS + n] =
                ((unsigned long long)mn2[j] << 32) | (unsigned long long)mn1[j];
    }
}

// Pure out = mem copy, 4 float4 per thread, fully coalesced.
__global__ void copy_mem(const float4* __restrict__ src, float4* __restrict__ dst) {
    int base = blockIdx.x * F4_PER_BLOCK + threadIdx.x;
    float4 v0 = src[base];
    float4 v1 = src[base + 256];
    float4 v2 = src[base + 512];
    float4 v3 = src[base + 768];
    dst[base]       = v0;
    dst[base + 256] = v1;
    dst[base + 512] = v2;
    dst[base + 768] = v3;
}

__device__ __forceinline__ int quant6(float d) {
    // match jnp: clip(round((d + 1)/2 * 63), 0, 63); jnp.round = half-to-even -> rintf
    float x = ((d + 1.0f) / 2.0f) * 63.0f;
    float r = rintf(x);
    r = fminf(fmaxf(r, 0.0f), 63.0f);
    return (int)r;
}

__global__ void finalize(const float* __restrict__ pts, const float* __restrict__ tex,
                         const int2* __restrict__ edges,
                         const unsigned long long* __restrict__ W,
                         float* __restrict__ out) {
    int n = blockIdx.x * blockDim.x + threadIdx.x;
    if (n >= N_PTS) return;

    // merge EP per-slice (m1,m2) pairs -> global two smallest (all indices distinct)
    unsigned int k1 = 0xFFFFFFFFu, k2 = 0xFFFFFFFFu;
    #pragma unroll
    for (int s = 0; s < EP; ++s) {
        unsigned long long pr = W[(size_t)s * N_PTS + n];
        unsigned int m1 = (unsigned int)(pr & 0xFFFFFFFFu);
        unsigned int m2 = (unsigned int)(pr >> 32);
        if (m1 < k1) { k2 = k1; k1 = m1; } else if (m1 < k2) { k2 = m1; }
        if (m2 < k2 && m2 > k1) { k2 = m2; }
    }

    float px = pts[2 * n], py = pts[2 * n + 1];
    int t = (tex[n] > 0.7f) ? 1 : 0;

    int v0x = 0, v0y = 0, t0 = 0, v1x = 0, v1y = 0, t1 = 0;

    if (k1 < 2u * N_EDGES) {
        int k = (int)k1;
        int2 e = edges[(k < N_EDGES) ? k : (k - N_EDGES)];
        int dst = (k < N_EDGES) ? e.y : e.x;
        v0x = quant6(pts[2 * dst] - px);
        v0y = quant6(pts[2 * dst + 1] - py);
        t0 = (tex[dst] > 0.7f) ? 1 : 0;
    }
    if (k2 < 2u * N_EDGES) {
        int k = (int)k2;
        int2 e = edges[(k < N_EDGES) ? k : (k - N_EDGES)];
        int dst = (k < N_EDGES) ? e.y : e.x;
        v1x = quant6(pts[2 * dst] - px);
        v1y = quant6(pts[2 * dst + 1] - py);
        t1 = (tex[dst] > 0.7f) ? 1 : 0;
    }

    // hash keeps only cols 0..4 (col4 masked to 3 bits); each rel-variant
    // appears 6 times in rel_all (2 builds x 3 identity-rolls / 3 swap-rolls).
    int h_id = t | (v0x << 6) | (v0y << 12) | (t0 << 18) | ((v1x & 7) << 24);
    int h_sw = t | (v1x << 6) | (v1y << 12) | (t1 << 18) | ((v0x & 7) << 24);

    atomicAdd(&out[h_id], 6.0f);
    atomicAdd(&out[h_sw], 6.0f);
}

extern "C" void kernel_launch(void* const* d_in, const int* in_sizes, int n_in,
                              void* d_out, int out_size, void* d_ws, size_t ws_size,
                              hipStream_t stream) {
    const float* pts   = (const float*)d_in[0];
    const float* tex   = (const float*)d_in[1];
    const int2*  edges = (const int2*)d_in[2];   // int64 in ref -> int32 on device
    const float* mem   = (const float*)d_in[3];
    float*       out   = (float*)d_out;

    unsigned long long* W = (unsigned long long*)d_ws;   // 16 * 200K * 8B = 25.6 MB

    const int B = 256;
    scan_2min<<<NP * EP, B, 0, stream>>>(edges, W);
    copy_mem<<<COPY_BLOCKS, B, 0, stream>>>((const float4*)mem, (float4*)out);
    finalize<<<(N_PTS + B - 1) / B, B, 0, stream>>>(pts, tex, edges, W, out);
}

// Round 9
// 279.863 us; speedup vs baseline: 1.5891x; 1.5891x over previous
//
#include <hip/hip_runtime.h>

#define N_PTS   200000
#define N_EDGES 1600000
#define MEM_SIZE (1 << 27)

#define COPY_BLOCKS  32768                    // 33,554,432 float4 / (256 thr * 4 per thr)
#define F4_PER_BLOCK 1024

#define NP   25                               // node parts
#define NPB  8192                             // nodes per part; 64KB LDS -> 2 blocks/CU
#define EP   16                               // edge slices
#define EPS  (N_EDGES / EP)                   // 100000 edges per slice
#define EPS4 (EPS / 2)                        // 50000 int4 (2 edges) per slice
#define SCAN_T 1024                           // 16 waves/block * 2 blocks/CU = 8 waves/SIMD

// Per-(edge-slice, node-range) 2-min in LDS; ZERO global atomics.
// rtn-min trick: old=atomicMin(min1,i); cand=(i<old)?old:i; atomicMin(min2,cand).
// Block (np,ep) owns W[ep][np-range] exclusively -> plain coalesced stores.
__global__ __launch_bounds__(SCAN_T) void scan_2min(const int4* __restrict__ edges4,
                                                    unsigned long long* __restrict__ W) {
    __shared__ unsigned mn1[NPB];
    __shared__ unsigned mn2[NPB];

    int b  = blockIdx.x;
    int ep = b / NP;                 // consecutive blocks share an edge slice (L2 reuse)
    int np = b % NP;
    int lo = np * NPB;

    for (int j = threadIdx.x; j < NPB; j += SCAN_T) { mn1[j] = 0xFFFFFFFFu; mn2[j] = 0xFFFFFFFFu; }
    __syncthreads();

    int q0 = ep * EPS4;              // slice start, in int4 units (2 edges each)
    for (int k = threadIdx.x; k < EPS4; k += SCAN_T) {
        int4 p = edges4[q0 + k];     // edges 2k, 2k+1 of this slice
        int i0 = ep * EPS + 2 * k;
        // edge i0: (p.x, p.y); edge i0+1: (p.z, p.w)
        int ax = p.x - lo;
        if ((unsigned)ax < NPB) {
            unsigned ia = (unsigned)i0;
            unsigned old = atomicMin(&mn1[ax], ia);
            unsigned c = (ia < old) ? old : ia;
            if (c != 0xFFFFFFFFu) atomicMin(&mn2[ax], c);
        }
        int ay = p.y - lo;
        if ((unsigned)ay < NPB) {
            unsigned ib = (unsigned)(i0 + N_EDGES);
            unsigned old = atomicMin(&mn1[ay], ib);
            unsigned c = (ib < old) ? old : ib;
            if (c != 0xFFFFFFFFu) atomicMin(&mn2[ay], c);
        }
        int az = p.z - lo;
        if ((unsigned)az < NPB) {
            unsigned ia = (unsigned)(i0 + 1);
            unsigned old = atomicMin(&mn1[az], ia);
            unsigned c = (ia < old) ? old : ia;
            if (c != 0xFFFFFFFFu) atomicMin(&mn2[az], c);
        }
        int aw = p.w - lo;
        if ((unsigned)aw < NPB) {
            unsigned ib = (unsigned)(i0 + 1 + N_EDGES);
            unsigned old = atomicMin(&mn1[aw], ib);
            unsigned c = (ib < old) ? old : ib;
            if (c != 0xFFFFFFFFu) atomicMin(&mn2[aw], c);
        }
    }
    __syncthreads();

    for (int j = threadIdx.x; j < NPB; j += SCAN_T) {
        int n = lo + j;
        if (n < N_PTS)
            W[(size_t)ep * N_PTS + n] =
                ((unsigned long long)mn2[j] << 32) | (unsigned long long)mn1[j];
    }
}

// Pure out = mem copy, 4 float4 per thread, fully coalesced.
__global__ void copy_mem(const float4* __restrict__ src, float4* __restrict__ dst) {
    int base = blockIdx.x * F4_PER_BLOCK + threadIdx.x;
    float4 v0 = src[base];
    float4 v1 = src[base + 256];
    float4 v2 = src[base + 512];
    float4 v3 = src[base + 768];
    dst[base]       = v0;
    dst[base + 256] = v1;
    dst[base + 512] = v2;
    dst[base + 768] = v3;
}

__device__ __forceinline__ int quant6(float d) {
    // match jnp: clip(round((d + 1)/2 * 63), 0, 63); jnp.round = half-to-even -> rintf
    float x = ((d + 1.0f) / 2.0f) * 63.0f;
    float r = rintf(x);
    r = fminf(fmaxf(r, 0.0f), 63.0f);
    return (int)r;
}

__global__ void finalize(const float* __restrict__ pts, const float* __restrict__ tex,
                         const int2* __restrict__ edges,
                         const unsigned long long* __restrict__ W,
                         float* __restrict__ out) {
    int n = blockIdx.x * blockDim.x + threadIdx.x;
    if (n >= N_PTS) return;

    // merge EP per-slice (m1,m2) pairs -> global two smallest (all indices distinct)
    unsigned int k1 = 0xFFFFFFFFu, k2 = 0xFFFFFFFFu;
    #pragma unroll
    for (int s = 0; s < EP; ++s) {
        unsigned long long pr = W[(size_t)s * N_PTS + n];
        unsigned int m1 = (unsigned int)(pr & 0xFFFFFFFFu);
        unsigned int m2 = (unsigned int)(pr >> 32);
        if (m1 < k1) { k2 = k1; k1 = m1; } else if (m1 < k2) { k2 = m1; }
        if (m2 < k2 && m2 > k1) { k2 = m2; }
    }

    float px = pts[2 * n], py = pts[2 * n + 1];
    int t = (tex[n] > 0.7f) ? 1 : 0;

    int v0x = 0, v0y = 0, t0 = 0, v1x = 0, v1y = 0, t1 = 0;

    if (k1 < 2u * N_EDGES) {
        int k = (int)k1;
        int2 e = edges[(k < N_EDGES) ? k : (k - N_EDGES)];
        int dst = (k < N_EDGES) ? e.y : e.x;
        v0x = quant6(pts[2 * dst] - px);
        v0y = quant6(pts[2 * dst + 1] - py);
        t0 = (tex[dst] > 0.7f) ? 1 : 0;
    }
    if (k2 < 2u * N_EDGES) {
        int k = (int)k2;
        int2 e = edges[(k < N_EDGES) ? k : (k - N_EDGES)];
        int dst = (k < N_EDGES) ? e.y : e.x;
        v1x = quant6(pts[2 * dst] - px);
        v1y = quant6(pts[2 * dst + 1] - py);
        t1 = (tex[dst] > 0.7f) ? 1 : 0;
    }

    // hash keeps only cols 0..4 (col4 masked to 3 bits); each rel-variant
    // appears 6 times in rel_all (2 builds x 3 identity-rolls / 3 swap-rolls).
    int h_id = t | (v0x << 6) | (v0y << 12) | (t0 << 18) | ((v1x & 7) << 24);
    int h_sw = t | (v1x << 6) | (v1y << 12) | (t1 << 18) | ((v0x & 7) << 24);

    atomicAdd(&out[h_id], 6.0f);
    atomicAdd(&out[h_sw], 6.0f);
}

extern "C" void kernel_launch(void* const* d_in, const int* in_sizes, int n_in,
                              void* d_out, int out_size, void* d_ws, size_t ws_size,
                              hipStream_t stream) {
    const float* pts   = (const float*)d_in[0];
    const float* tex   = (const float*)d_in[1];
    const int2*  edges = (const int2*)d_in[2];   // int64 in ref -> int32 on device
    const float* mem   = (const float*)d_in[3];
    float*       out   = (float*)d_out;

    unsigned long long* W = (unsigned long long*)d_ws;   // 16 * 200K * 8B = 25.6 MB

    scan_2min<<<NP * EP, SCAN_T, 0, stream>>>((const int4*)edges, W);
    copy_mem<<<COPY_BLOCKS, 256, 0, stream>>>((const float4*)mem, (float4*)out);
    finalize<<<(N_PTS + 255) / 256, 256, 0, stream>>>(pts, tex, edges, W, out);
}

// Round 10
// 273.122 us; speedup vs baseline: 1.6284x; 1.0247x over previous
//
#include <hip/hip_runtime.h>

#define N_PTS   200000
#define N_EDGES 1600000
#define MEM_SIZE (1 << 27)

#define COPY_BLOCKS  32768                    // 33,554,432 float4 / (256 thr * 4 per thr)
#define F4_PER_BLOCK 1024

#define NP   25                               // node parts
#define NPB  8192                             // nodes per part; 64KB LDS -> 2 blocks/CU
#define EP   16                               // edge slices (W = 25.6 MB, proven ws fit)
#define EPS  (N_EDGES / EP)                   // 100000 edges per slice
#define EPS4 (EPS / 2)                        // 50000 int4 (2 edges) per slice
#define SCAN_T 1024                           // 16 waves/block * 2 blocks/CU = 8 waves/SIMD

__device__ __forceinline__ void upd2(unsigned* __restrict__ mn1, unsigned* __restrict__ mn2,
                                     int a, unsigned i) {
    if ((unsigned)a < NPB) {
        unsigned old = atomicMin(&mn1[a], i);
        unsigned c = (i < old) ? old : i;      // displaced value or losing insert
        if (c != 0xFFFFFFFFu) atomicMin(&mn2[a], c);
    }
}

__device__ __forceinline__ void proc(unsigned* __restrict__ mn1, unsigned* __restrict__ mn2,
                                     int lo, int4 p, int g /* int4 index */) {
    // int4 g holds edges 2g (p.x,p.y) and 2g+1 (p.z,p.w)
    unsigned ia0 = (unsigned)(2 * g);
    unsigned ib0 = (unsigned)(2 * g + N_EDGES);
    upd2(mn1, mn2, p.x - lo, ia0);
    upd2(mn1, mn2, p.y - lo, ib0);
    upd2(mn1, mn2, p.z - lo, ia0 + 1u);
    upd2(mn1, mn2, p.w - lo, ib0 + 1u);
}

// Per-(edge-slice, node-range) 2-min in LDS; zero global atomics.
// 4-deep load batching: 4 independent int4 loads in flight per wave
// (32 per SIMD) to cover the ~1K-cycle LLC/HBM load latency that made the
// 1-deep version stall-bound (~95us for ~15us of work).
__global__ __launch_bounds__(SCAN_T) void scan_2min(const int4* __restrict__ edges4,
                                                    unsigned long long* __restrict__ W) {
    __shared__ unsigned mn1[NPB];
    __shared__ unsigned mn2[NPB];

    int b  = blockIdx.x;
    int ep = b / NP;                 // consecutive blocks share an edge slice (L2 reuse)
    int np = b % NP;
    int lo = np * NPB;

    for (int j = threadIdx.x; j < NPB; j += SCAN_T) { mn1[j] = 0xFFFFFFFFu; mn2[j] = 0xFFFFFFFFu; }
    __syncthreads();

    int q0 = ep * EPS4;              // slice start, int4 units
    int k = threadIdx.x;
    for (; k + 3 * SCAN_T < EPS4; k += 4 * SCAN_T) {
        int g0 = q0 + k;
        int4 p0 = edges4[g0];
        int4 p1 = edges4[g0 + SCAN_T];
        int4 p2 = edges4[g0 + 2 * SCAN_T];
        int4 p3 = edges4[g0 + 3 * SCAN_T];
        proc(mn1, mn2, lo, p0, g0);
        proc(mn1, mn2, lo, p1, g0 + SCAN_T);
        proc(mn1, mn2, lo, p2, g0 + 2 * SCAN_T);
        proc(mn1, mn2, lo, p3, g0 + 3 * SCAN_T);
    }
    for (; k < EPS4; k += SCAN_T) {
        int g = q0 + k;
        int4 p = edges4[g];
        proc(mn1, mn2, lo, p, g);
    }
    __syncthreads();

    for (int j = threadIdx.x; j < NPB; j += SCAN_T) {
        int n = lo + j;
        if (n < N_PTS)
            W[(size_t)ep * N_PTS + n] =
                ((unsigned long long)mn2[j] << 32) | (unsigned long long)mn1[j];
    }
}

// Pure out = mem copy, 4 float4 per thread, fully coalesced (measured ~roofline).
__global__ void copy_mem(const float4* __restrict__ src, float4* __restrict__ dst) {
    int base = blockIdx.x * F4_PER_BLOCK + threadIdx.x;
    float4 v0 = src[base];
    float4 v1 = src[base + 256];
    float4 v2 = src[base + 512];
    float4 v3 = src[base + 768];
    dst[base]       = v0;
    dst[base + 256] = v1;
    dst[base + 512] = v2;
    dst[base + 768] = v3;
}

__device__ __forceinline__ int quant6(float d) {
    // match jnp: clip(round((d + 1)/2 * 63), 0, 63); jnp.round = half-to-even -> rintf
    float x = ((d + 1.0f) / 2.0f) * 63.0f;
    float r = rintf(x);
    r = fminf(fmaxf(r, 0.0f), 63.0f);
    return (int)r;
}

__global__ void finalize(const float* __restrict__ pts, const float* __restrict__ tex,
                         const int2* __restrict__ edges,
                         const unsigned long long* __restrict__ W,
                         float* __restrict__ out) {
    int n = blockIdx.x * blockDim.x + threadIdx.x;
    if (n >= N_PTS) return;

    // merge EP per-slice (m1,m2) pairs -> global two smallest (all indices distinct)
    unsigned int k1 = 0xFFFFFFFFu, k2 = 0xFFFFFFFFu;
    #pragma unroll
    for (int s = 0; s < EP; ++s) {
        unsigned long long pr = W[(size_t)s * N_PTS + n];
        unsigned int m1 = (unsigned int)(pr & 0xFFFFFFFFu);
        unsigned int m2 = (unsigned int)(pr >> 32);
        if (m1 < k1) { k2 = k1; k1 = m1; } else if (m1 < k2) { k2 = m1; }
        if (m2 < k2 && m2 > k1) { k2 = m2; }
    }

    float px = pts[2 * n], py = pts[2 * n + 1];
    int t = (tex[n] > 0.7f) ? 1 : 0;

    int v0x = 0, v0y = 0, t0 = 0, v1x = 0, v1y = 0, t1 = 0;

    if (k1 < 2u * N_EDGES) {
        int k = (int)k1;
        int2 e = edges[(k < N_EDGES) ? k : (k - N_EDGES)];
        int dst = (k < N_EDGES) ? e.y : e.x;
        v0x = quant6(pts[2 * dst] - px);
        v0y = quant6(pts[2 * dst + 1] - py);
        t0 = (tex[dst] > 0.7f) ? 1 : 0;
    }
    if (k2 < 2u * N_EDGES) {
        int k = (int)k2;
        int2 e = edges[(k < N_EDGES) ? k : (k - N_EDGES)];
        int dst = (k < N_EDGES) ? e.y : e.x;
        v1x = quant6(pts[2 * dst] - px);
        v1y = quant6(pts[2 * dst + 1] - py);
        t1 = (tex[dst] > 0.7f) ? 1 : 0;
    }

    // hash keeps only cols 0..4 (col4 masked to 3 bits); each rel-variant
    // appears 6 times in rel_all (2 builds x 3 identity-rolls / 3 swap-rolls).
    int h_id = t | (v0x << 6) | (v0y << 12) | (t0 << 18) | ((v1x & 7) << 24);
    int h_sw = t | (v1x << 6) | (v1y << 12) | (t1 << 18) | ((v0x & 7) << 24);

    atomicAdd(&out[h_id], 6.0f);
    atomicAdd(&out[h_sw], 6.0f);
}

extern "C" void kernel_launch(void* const* d_in, const int* in_sizes, int n_in,
                              void* d_out, int out_size, void* d_ws, size_t ws_size,
                              hipStream_t stream) {
    const float* pts   = (const float*)d_in[0];
    const float* tex   = (const float*)d_in[1];
    const int2*  edges = (const int2*)d_in[2];   // int64 in ref -> int32 on device
    const float* mem   = (const float*)d_in[3];
    float*       out   = (float*)d_out;

    unsigned long long* W = (unsigned long long*)d_ws;   // 16 * 200K * 8B = 25.6 MB

    scan_2min<<<NP * EP, SCAN_T, 0, stream>>>((const int4*)edges, W);
    copy_mem<<<COPY_BLOCKS, 256, 0, stream>>>((const float4*)mem, (float4*)out);
    finalize<<<(N_PTS + 255) / 256, 256, 0, stream>>>(pts, tex, edges, W, out);
}

// Round 11
// 261.327 us; speedup vs baseline: 1.7019x; 1.0451x over previous
//
#include <hip/hip_runtime.h>

#define N_PTS   200000
#define N_EDGES 1600000
#define MEM_SIZE (1 << 27)

#define NP   32                               // node parts
#define NPB  6400                             // nodes/part (32*6400 = 204800 >= 200000)
#define EP   16                               // edge slices; W = 16*200K*8B = 25.6 MB
#define EPS  (N_EDGES / EP)                   // 100000 edges per slice
#define EPS4 (EPS / 2)                        // 50000 int4 (2 edges) per slice
#define NBLK (NP * EP)                        // 512 blocks = exactly 2 per CU
#define NTHR 1024                             // 32 waves/CU with 2 blocks/CU (max occ)
#define NF4  (MEM_SIZE / 4)                   // 33,554,432 float4
#define CSTRIDE (NBLK * NTHR)                 // 524,288 threads -> 64 f4/thread exact
#define CITER (NF4 / CSTRIDE)                 // 64
#define SITER ((EPS4 + NTHR - 1) / NTHR)      // 49

__device__ __forceinline__ void upd2(unsigned* __restrict__ mn1, unsigned* __restrict__ mn2,
                                     int a, unsigned i) {
    if ((unsigned)a < NPB) {
        unsigned old = atomicMin(&mn1[a], i);
        unsigned c = (i < old) ? old : i;      // displaced value or losing insert
        if (c != 0xFFFFFFFFu) atomicMin(&mn2[a], c);
    }
}

__device__ __forceinline__ void proc(unsigned* __restrict__ mn1, unsigned* __restrict__ mn2,
                                     int lo, int4 p, int g /* global int4 index */) {
    // int4 g holds edges 2g (p.x,p.y) and 2g+1 (p.z,p.w)
    unsigned ia0 = (unsigned)(2 * g);
    unsigned ib0 = (unsigned)(2 * g + N_EDGES);
    upd2(mn1, mn2, p.x - lo, ia0);
    upd2(mn1, mn2, p.y - lo, ib0);
    upd2(mn1, mn2, p.z - lo, ia0 + 1u);
    upd2(mn1, mn2, p.w - lo, ib0 + 1u);
}

// Fused: out=mem copy (HBM-bound) + per-(slice,node-part) LDS 2-min scan.
// Scan's LDS-atomic/VALU/L2-read work hides under the copy's HBM streaming —
// per-CU resources, unlike round-5's fabric-serialized global atomics.
__global__ __launch_bounds__(NTHR) void fused_copy_scan(const float4* __restrict__ src,
                                                        float4* __restrict__ dst,
                                                        const int4* __restrict__ edges4,
                                                        unsigned long long* __restrict__ W) {
    __shared__ unsigned mn1[NPB];
    __shared__ unsigned mn2[NPB];

    int b  = blockIdx.x;
    int ep = b >> 5;                 // b / NP
    int np = b & 31;                 // b % NP
    int lo = np * NPB;
    int t  = threadIdx.x;

    for (int j = t; j < NPB; j += NTHR) { mn1[j] = 0xFFFFFFFFu; mn2[j] = 0xFFFFFFFFu; }
    __syncthreads();

    int q0 = ep * EPS4;              // slice start, int4 units
    int cbase = b * NTHR + t;        // copy index, stride CSTRIDE

    #pragma unroll 4
    for (int j = 0; j < CITER; ++j) {
        int ci = cbase + j * CSTRIDE;
        float4 v = src[ci];
        int k = t + j * NTHR;
        bool have = (j < SITER) && (k < EPS4);
        int4 p;
        if (have) p = edges4[q0 + k];
        dst[ci] = v;
        if (have) proc(mn1, mn2, lo, p, q0 + k);
    }
    __syncthreads();

    for (int j = t; j < NPB; j += NTHR) {
        int n = lo + j;
        if (n < N_PTS)
            W[(size_t)ep * N_PTS + n] =
                ((unsigned long long)mn2[j] << 32) | (unsigned long long)mn1[j];
    }
}

__device__ __forceinline__ int quant6(float d) {
    // match jnp: clip(round((d + 1)/2 * 63), 0, 63); jnp.round = half-to-even -> rintf
    float x = ((d + 1.0f) / 2.0f) * 63.0f;
    float r = rintf(x);
    r = fminf(fmaxf(r, 0.0f), 63.0f);
    return (int)r;
}

__global__ void finalize(const float* __restrict__ pts, const float* __restrict__ tex,
                         const int2* __restrict__ edges,
                         const unsigned long long* __restrict__ W,
                         float* __restrict__ out) {
    int n = blockIdx.x * blockDim.x + threadIdx.x;
    if (n >= N_PTS) return;

    // merge EP per-slice (m1,m2) pairs -> global two smallest (all indices distinct)
    unsigned int k1 = 0xFFFFFFFFu, k2 = 0xFFFFFFFFu;
    #pragma unroll
    for (int s = 0; s < EP; ++s) {
        unsigned long long pr = W[(size_t)s * N_PTS + n];
        unsigned int m1 = (unsigned int)(pr & 0xFFFFFFFFu);
        unsigned int m2 = (unsigned int)(pr >> 32);
        if (m1 < k1) { k2 = k1; k1 = m1; } else if (m1 < k2) { k2 = m1; }
        if (m2 < k2 && m2 > k1) { k2 = m2; }
    }

    float px = pts[2 * n], py = pts[2 * n + 1];
    int t = (tex[n] > 0.7f) ? 1 : 0;

    int v0x = 0, v0y = 0, t0 = 0, v1x = 0, v1y = 0, t1 = 0;

    if (k1 < 2u * N_EDGES) {
        int k = (int)k1;
        int2 e = edges[(k < N_EDGES) ? k : (k - N_EDGES)];
        int dst = (k < N_EDGES) ? e.y : e.x;
        v0x = quant6(pts[2 * dst] - px);
        v0y = quant6(pts[2 * dst + 1] - py);
        t0 = (tex[dst] > 0.7f) ? 1 : 0;
    }
    if (k2 < 2u * N_EDGES) {
        int k = (int)k2;
        int2 e = edges[(k < N_EDGES) ? k : (k - N_EDGES)];
        int dst = (k < N_EDGES) ? e.y : e.x;
        v1x = quant6(pts[2 * dst] - px);
        v1y = quant6(pts[2 * dst + 1] - py);
        t1 = (tex[dst] > 0.7f) ? 1 : 0;
    }

    // hash keeps only cols 0..4 (col4 masked to 3 bits); each rel-variant
    // appears 6 times in rel_all (2 builds x 3 identity-rolls / 3 swap-rolls).
    int h_id = t | (v0x << 6) | (v0y << 12) | (t0 << 18) | ((v1x & 7) << 24);
    int h_sw = t | (v1x << 6) | (v1y << 12) | (t1 << 18) | ((v0x & 7) << 24);

    atomicAdd(&out[h_id], 6.0f);
    atomicAdd(&out[h_sw], 6.0f);
}

extern "C" void kernel_launch(void* const* d_in, const int* in_sizes, int n_in,
                              void* d_out, int out_size, void* d_ws, size_t ws_size,
                              hipStream_t stream) {
    const float* pts   = (const float*)d_in[0];
    const float* tex   = (const float*)d_in[1];
    const int2*  edges = (const int2*)d_in[2];   // int64 in ref -> int32 on device
    const float* mem   = (const float*)d_in[3];
    float*       out   = (float*)d_out;

    unsigned long long* W = (unsigned long long*)d_ws;   // 16 * 200K * 8B = 25.6 MB

    fused_copy_scan<<<NBLK, NTHR, 0, stream>>>(
        (const float4*)mem, (float4*)out, (const int4*)edges, W);
    finalize<<<(N_PTS + 255) / 256, 256, 0, stream>>>(pts, tex, edges, W, out);
}